// Round 4
// baseline (957.815 us; speedup 1.0000x reference)
//
#include <hip/hip_runtime.h>
#include <cstdint>
#include <cstddef>

// LSTM: B=32, T=1024, D=1024, H=128, gates 4H=512. Gate order i,f,g,o.
// Plan:
//   prep:     W_ih fp32 -> fp16, bsum = b_ih + b_hh
//   gemm_gx:  gx[BT=32768][512] = x @ W_ih^T + bsum   (fp16 MFMA, fp32 acc)
//   lstm_rec: 32 blocks (one per batch), sequential over T; W_hh rows in VGPRs,
//             h broadcast via LDS, c in registers of threads t<128.

typedef __attribute__((ext_vector_type(8))) _Float16 half8;
typedef __attribute__((ext_vector_type(4))) _Float16 half4;
typedef __attribute__((ext_vector_type(4))) float    f32x4;

#define BT    32768   // B*T
#define DD    1024
#define GG    512     // 4*H
#define HH    128
#define TT    1024
#define BB    32

// ---------------- prep: convert W_ih to fp16, bias sum ----------------
__global__ void prep_kernel(const float* __restrict__ wih,
                            const float* __restrict__ bih,
                            const float* __restrict__ bhh,
                            _Float16* __restrict__ wih_h,
                            float* __restrict__ bsum) {
    int i = blockIdx.x * 256 + threadIdx.x;   // grid covers 512*1024 exactly
    wih_h[i] = (_Float16)wih[i];
    if (i < GG) bsum[i] = bih[i] + bhh[i];
}

// ---------------- GEMM: gx = x @ W_ih^T + bsum ----------------
// A = x [BT x DD] row-major (K-contig), B = W_ih fp16 [GG x DD] row-major (K-contig).
// Tile 128x128, BK=32, 256 threads = 4 waves (2x2), each wave 64x64 = 4x4 frags.
#define BM 128
#define BN 128
#define BK 32
#define LDP 40   // LDS row pitch in halves (32 + 8 pad -> 80B rows, 2-way bank alias = free)

__global__ __launch_bounds__(256)
void gemm_gx(const float* __restrict__ x, const _Float16* __restrict__ wih_h,
             const float* __restrict__ bsum, float* __restrict__ gx) {
    const int bid = blockIdx.x;
    const int m0 = (bid >> 2) * BM;      // 256 m-tiles
    const int n0 = (bid & 3) * BN;       // 4 n-tiles
    const int t  = threadIdx.x;
    const int lane = t & 63;
    const int w  = t >> 6;
    const int wr = w >> 1, wc = w & 1;
    const int lr = lane & 15;            // row/col within 16
    const int lk = lane >> 4;            // k-group 0..3

    __shared__ __align__(16) _Float16 As[BM][LDP];
    __shared__ __align__(16) _Float16 Bs[BN][LDP];

    f32x4 acc[4][4] = {};

    for (int kt = 0; kt < DD; kt += BK) {
        // ---- stage A: 128 rows x 32 halves (convert fp32->fp16 in flight) ----
        #pragma unroll
        for (int pass = 0; pass < 4; ++pass) {
            int r = pass * 32 + (t >> 3);
            int c = (t & 7) * 4;
            float4 v = *(const float4*)(x + (size_t)(m0 + r) * DD + kt + c);
            half4 hv;
            hv[0] = (_Float16)v.x; hv[1] = (_Float16)v.y;
            hv[2] = (_Float16)v.z; hv[3] = (_Float16)v.w;
            *(half4*)&As[r][c] = hv;
        }
        // ---- stage B: 128 rows x 32 halves (already fp16) ----
        #pragma unroll
        for (int pass = 0; pass < 2; ++pass) {
            int r = pass * 64 + (t >> 2);
            int c = (t & 3) * 8;
            float4 v = *(const float4*)(wih_h + (size_t)(n0 + r) * DD + kt + c);
            *(float4*)&Bs[r][c] = v;
        }
        __syncthreads();

        // ---- fragments: lane l holds 8 contiguous k at row (l&15), k-off 8*(l>>4) ----
        half8 af[4], bf[4];
        #pragma unroll
        for (int i = 0; i < 4; ++i)
            af[i] = *(const half8*)&As[wr * 64 + i * 16 + lr][lk * 8];
        #pragma unroll
        for (int j = 0; j < 4; ++j)
            bf[j] = *(const half8*)&Bs[wc * 64 + j * 16 + lr][lk * 8];

        #pragma unroll
        for (int i = 0; i < 4; ++i)
            #pragma unroll
            for (int j = 0; j < 4; ++j)
                acc[i][j] = __builtin_amdgcn_mfma_f32_16x16x32_f16(af[i], bf[j], acc[i][j], 0, 0, 0);
        __syncthreads();
    }

    // ---- epilogue: C/D mapping col = lane&15, row = 4*(lane>>4) + reg ----
    #pragma unroll
    for (int j = 0; j < 4; ++j) {
        int n = n0 + wc * 64 + j * 16 + lr;
        float bn = bsum[n];
        #pragma unroll
        for (int i = 0; i < 4; ++i) {
            int mbase = m0 + wr * 64 + i * 16 + lk * 4;
            #pragma unroll
            for (int r = 0; r < 4; ++r)
                gx[(size_t)(mbase + r) * GG + n] = acc[i][j][r] + bn;
        }
    }
}

// ---------------- recurrence ----------------
// One block per batch element. Thread t owns gate row t (0..511).
// W_hh row t (128 floats) lives in VGPRs; h broadcast via LDS (uniform reads);
// threads t<128 own c_t / h_t.
__global__ __launch_bounds__(512)
void lstm_rec(const float* __restrict__ gx, const float* __restrict__ whh,
              float* __restrict__ out, float* __restrict__ hn, float* __restrict__ cn) {
    const int b = blockIdx.x;
    const int t = threadIdx.x;

    __shared__ __align__(16) float hsf[HH];
    __shared__ float acts[GG];

    // W_hh row t -> registers (128 floats, statically indexed)
    float wv[HH];
    #pragma unroll
    for (int p = 0; p < 32; ++p) {
        float4 v = *(const float4*)(whh + (size_t)t * HH + p * 4);
        wv[4 * p + 0] = v.x; wv[4 * p + 1] = v.y;
        wv[4 * p + 2] = v.z; wv[4 * p + 3] = v.w;
    }

    float c = 0.f, hval = 0.f;
    if (t < HH) hsf[t] = 0.f;
    __syncthreads();

    const float* gxp  = gx + (size_t)b * TT * GG + t;
    float*       outp = out + (size_t)b * TT * HH;

    for (int step = 0; step < TT; ++step) {
        float pre = gxp[(size_t)step * GG];   // issued early; hides under dot

        // dot(wv, h_prev): 32x ds_read_b128 broadcast + 128 fma, 4 partial chains
        float a0 = 0.f, a1 = 0.f, a2 = 0.f, a3 = 0.f;
        #pragma unroll
        for (int q = 0; q < 32; ++q) {
            float4 hv = ((const float4*)hsf)[q];
            a0 = fmaf(wv[4 * q + 0], hv.x, a0);
            a1 = fmaf(wv[4 * q + 1], hv.y, a1);
            a2 = fmaf(wv[4 * q + 2], hv.z, a2);
            a3 = fmaf(wv[4 * q + 3], hv.w, a3);
        }
        pre += (a0 + a1) + (a2 + a3);

        // activations: waves 4-5 (t in [256,384)) take tanh -> wave-uniform branch
        float a;
        if (t >= 256 && t < 384) {
            a = 2.f / (1.f + __expf(-2.f * pre)) - 1.f;   // tanh(g)
        } else {
            a = 1.f / (1.f + __expf(-pre));               // sigmoid(i,f,o)
        }
        acts[t] = a;
        __syncthreads();   // all hsf reads done + acts visible

        if (t < HH) {
            float ig = acts[t];
            float fg = acts[HH + t];
            float gg = acts[2 * HH + t];
            float og = acts[3 * HH + t];
            c = fmaf(fg, c, ig * gg);
            float th = 2.f / (1.f + __expf(-2.f * c)) - 1.f;
            hval = og * th;
            hsf[t] = hval;
            outp[(size_t)step * HH + t] = hval;
        }
        __syncthreads();   // hsf update visible to next iteration
    }

    if (t < HH) {
        hn[b * HH + t] = hval;
        cn[b * HH + t] = c;
    }
}

// ---------------- launch ----------------
extern "C" void kernel_launch(void* const* d_in, const int* in_sizes, int n_in,
                              void* d_out, int out_size, void* d_ws, size_t ws_size,
                              hipStream_t stream) {
    const float* x   = (const float*)d_in[0];
    const float* wih = (const float*)d_in[1];
    const float* whh = (const float*)d_in[2];
    const float* bih = (const float*)d_in[3];
    const float* bhh = (const float*)d_in[4];
    float* out = (float*)d_out;

    // workspace layout: [W_ih fp16: 1MB][bsum: 4KB pad][gx fp32: 64MB]  (~68.2MB)
    char* ws = (char*)d_ws;
    _Float16* wih_h = (_Float16*)ws;
    float*    bsum  = (float*)(ws + (size_t)(1 << 20));
    float*    gx    = (float*)(ws + (size_t)(1 << 20) + 4096);

    prep_kernel<<<(GG * DD) / 256, 256, 0, stream>>>(wih, bih, bhh, wih_h, bsum);
    gemm_gx<<<(BT / BM) * (GG / BN), 256, 0, stream>>>(x, wih_h, bsum, gx);

    float* hn = out + (size_t)BB * TT * HH;            // 4194304
    float* cn = hn + BB * HH;                          // +4096
    lstm_rec<<<BB, 512, 0, stream>>>(gx, whh, out, hn, cn);
}

// Round 5
// 749.009 us; speedup vs baseline: 1.2788x; 1.2788x over previous
//
#include <hip/hip_runtime.h>
#include <hip/hip_fp16.h>
#include <cstdint>
#include <cstddef>

// LSTM: B=32, T=1024, D=1024, H=128, gates 4H=512 (order i,f,g,o).
//   prep:     W_ih fp32->fp16, W_hh fp32->fp16, bsum = b_ih + b_hh
//   gemm_gx:  gx[32768][512] = x @ W_ih^T + bsum   (fp16 MFMA, fp32 acc)
//   lstm_rec: 32 blocks (1/batch) x 512 threads; thread t = 4*j + gate.
//             W_hh row in VGPRs (fp16), dot via v_pk_fma_f16, h double-buffered
//             in LDS, gate exchange via shfl_xor, ONE raw s_barrier per step
//             (lgkmcnt-only drain; gx prefetched one step ahead in registers).

typedef __attribute__((ext_vector_type(8))) _Float16 half8;
typedef __attribute__((ext_vector_type(4))) _Float16 half4;
typedef __attribute__((ext_vector_type(4))) float    f32x4;

#define BT    32768   // B*T
#define DD    1024
#define GG    512     // 4*H
#define HH    128
#define TT    1024
#define BB    32

// ---------------- prep: fp16 conversions + bias sum ----------------
__global__ void prep_kernel(const float* __restrict__ wih,
                            const float* __restrict__ whh,
                            const float* __restrict__ bih,
                            const float* __restrict__ bhh,
                            _Float16* __restrict__ wih_h,
                            __half*   __restrict__ whh_h,
                            float* __restrict__ bsum) {
    int i = blockIdx.x * 256 + threadIdx.x;   // grid covers 512*1024 exactly
    wih_h[i] = (_Float16)wih[i];
    if (i < GG * HH) whh_h[i] = __float2half(whh[i]);
    if (i < GG)      bsum[i] = bih[i] + bhh[i];
}

// ---------------- GEMM: gx = x @ W_ih^T + bsum (unchanged, verified) --------
#define BM 128
#define BN 128
#define BK 32
#define LDP 40   // LDS row pitch in halves (80B rows, 2-way bank alias = free)

__global__ __launch_bounds__(256)
void gemm_gx(const float* __restrict__ x, const _Float16* __restrict__ wih_h,
             const float* __restrict__ bsum, float* __restrict__ gx) {
    const int bid = blockIdx.x;
    const int m0 = (bid >> 2) * BM;
    const int n0 = (bid & 3) * BN;
    const int t  = threadIdx.x;
    const int lane = t & 63;
    const int w  = t >> 6;
    const int wr = w >> 1, wc = w & 1;
    const int lr = lane & 15;
    const int lk = lane >> 4;

    __shared__ __align__(16) _Float16 As[BM][LDP];
    __shared__ __align__(16) _Float16 Bs[BN][LDP];

    f32x4 acc[4][4] = {};

    for (int kt = 0; kt < DD; kt += BK) {
        #pragma unroll
        for (int pass = 0; pass < 4; ++pass) {
            int r = pass * 32 + (t >> 3);
            int c = (t & 7) * 4;
            float4 v = *(const float4*)(x + (size_t)(m0 + r) * DD + kt + c);
            half4 hv;
            hv[0] = (_Float16)v.x; hv[1] = (_Float16)v.y;
            hv[2] = (_Float16)v.z; hv[3] = (_Float16)v.w;
            *(half4*)&As[r][c] = hv;
        }
        #pragma unroll
        for (int pass = 0; pass < 2; ++pass) {
            int r = pass * 64 + (t >> 2);
            int c = (t & 3) * 8;
            float4 v = *(const float4*)(wih_h + (size_t)(n0 + r) * DD + kt + c);
            *(float4*)&Bs[r][c] = v;
        }
        __syncthreads();

        half8 af[4], bf[4];
        #pragma unroll
        for (int i = 0; i < 4; ++i)
            af[i] = *(const half8*)&As[wr * 64 + i * 16 + lr][lk * 8];
        #pragma unroll
        for (int j = 0; j < 4; ++j)
            bf[j] = *(const half8*)&Bs[wc * 64 + j * 16 + lr][lk * 8];

        #pragma unroll
        for (int i = 0; i < 4; ++i)
            #pragma unroll
            for (int j = 0; j < 4; ++j)
                acc[i][j] = __builtin_amdgcn_mfma_f32_16x16x32_f16(af[i], bf[j], acc[i][j], 0, 0, 0);
        __syncthreads();
    }

    #pragma unroll
    for (int j = 0; j < 4; ++j) {
        int n = n0 + wc * 64 + j * 16 + lr;
        float bn = bsum[n];
        #pragma unroll
        for (int i = 0; i < 4; ++i) {
            int mbase = m0 + wr * 64 + i * 16 + lk * 4;
            #pragma unroll
            for (int r = 0; r < 4; ++r)
                gx[(size_t)(mbase + r) * GG + n] = acc[i][j][r] + bn;
        }
    }
}

// ---------------- recurrence ----------------
// thread t: j = t>>2 (h index), gi = t&3 (0=i,1=f,2=g,3=o); gate row r = gi*128+j.
union F4H { float4 f; __half2 h[4]; };

__global__ __launch_bounds__(512)
void lstm_rec(const float* __restrict__ gx, const __half* __restrict__ whh_h,
              float* __restrict__ out, float* __restrict__ hn, float* __restrict__ cn) {
    const int b  = blockIdx.x;
    const int t  = threadIdx.x;
    const int j  = t >> 2;
    const int gi = t & 3;
    const int r  = gi * HH + j;

    __shared__ __align__(16) __half hbuf[2][HH];   // double-buffered h (2x256B)

    // W_hh row r -> 64 x __half2 in VGPRs
    __half2 wv[64];
    {
        const float4* wp = (const float4*)(whh_h + (size_t)r * HH);
        #pragma unroll
        for (int q = 0; q < 16; ++q) {
            F4H u; u.f = wp[q];
            wv[4 * q + 0] = u.h[0]; wv[4 * q + 1] = u.h[1];
            wv[4 * q + 2] = u.h[2]; wv[4 * q + 3] = u.h[3];
        }
    }

    // branchless activation constants: gate g (gi==2) is tanh = 2*sigma(2x)-1
    const float kneg = (gi == 2) ? -2.f : -1.f;
    const float k2   = (gi == 2) ?  2.f :  1.f;
    const float k3   = (gi == 2) ? -1.f :  0.f;

    if (t < HH) hbuf[0][t] = __float2half(0.f);
    __syncthreads();

    const float* gxp  = gx + (size_t)b * TT * GG + r;
    float*       outp = out + (size_t)b * TT * HH;

    float c = 0.f, hval = 0.f;
    float pre_cur = gxp[0];

    for (int step = 0; step < TT; ++step) {
        // prefetch next step's gate pre-activation (uniform-min clamp, no OOB)
        int sp = step + 1; if (sp >= TT) sp = TT - 1;
        float pre_nxt = gxp[(size_t)sp * GG];

        // dot(w_row, h_prev): 16x ds_read_b128 broadcast + 64x v_pk_fma_f16
        const float4* hp = (const float4*)hbuf[step & 1];
        __half2 acc[8];
        #pragma unroll
        for (int k = 0; k < 8; ++k) acc[k] = __float2half2_rn(0.f);
        #pragma unroll
        for (int q = 0; q < 16; ++q) {
            F4H u; u.f = hp[q];
            const int ab = (q & 1) * 4;
            acc[ab + 0] = __hfma2(wv[4 * q + 0], u.h[0], acc[ab + 0]);
            acc[ab + 1] = __hfma2(wv[4 * q + 1], u.h[1], acc[ab + 1]);
            acc[ab + 2] = __hfma2(wv[4 * q + 2], u.h[2], acc[ab + 2]);
            acc[ab + 3] = __hfma2(wv[4 * q + 3], u.h[3], acc[ab + 3]);
        }
        acc[0] = __hadd2(acc[0], acc[4]); acc[1] = __hadd2(acc[1], acc[5]);
        acc[2] = __hadd2(acc[2], acc[6]); acc[3] = __hadd2(acc[3], acc[7]);
        acc[0] = __hadd2(acc[0], acc[2]); acc[1] = __hadd2(acc[1], acc[3]);
        acc[0] = __hadd2(acc[0], acc[1]);
        float pre = pre_cur + __low2float(acc[0]) + __high2float(acc[0]);

        // activation (branchless): s = sigma(|kneg|*pre); a = k2*s + k3
        float s = __builtin_amdgcn_rcpf(1.f + __expf(pre * kneg));
        float a = fmaf(k2, s, k3);

        // in-wave gate exchange: lane gi==0 ends with (a=i, x1=f, x2=g, x3=o)
        float x1 = __shfl_xor(a, 1);
        float x2 = __shfl_xor(a, 2);
        float x3 = __shfl_xor(x1, 2);

        if (gi == 0) {
            c = fmaf(x1, c, a * x2);
            float th = fmaf(2.f, __builtin_amdgcn_rcpf(1.f + __expf(-2.f * c)), -1.f);
            hval = x3 * th;
            hbuf[(step + 1) & 1][j] = __float2half(hval);
            outp[(size_t)step * HH + j] = hval;
        }

        // one barrier per step: only LDS drain (no vmcnt -> store/prefetch
        // latency stays off the critical path)
        __builtin_amdgcn_sched_barrier(0);
        asm volatile("s_waitcnt lgkmcnt(0)" ::: "memory");
        __builtin_amdgcn_s_barrier();
        __builtin_amdgcn_sched_barrier(0);

        pre_cur = pre_nxt;
    }

    if (gi == 0) {
        hn[b * HH + j] = hval;
        cn[b * HH + j] = c;
    }
}

// ---------------- launch ----------------
extern "C" void kernel_launch(void* const* d_in, const int* in_sizes, int n_in,
                              void* d_out, int out_size, void* d_ws, size_t ws_size,
                              hipStream_t stream) {
    const float* x   = (const float*)d_in[0];
    const float* wih = (const float*)d_in[1];
    const float* whh = (const float*)d_in[2];
    const float* bih = (const float*)d_in[3];
    const float* bhh = (const float*)d_in[4];
    float* out = (float*)d_out;

    // ws layout: [W_ih fp16 1MB][W_hh fp16 128KB][bsum 2KB pad->4KB][gx fp32 64MB]
    char* ws = (char*)d_ws;
    _Float16* wih_h = (_Float16*)ws;
    __half*   whh_h = (__half*)(ws + (size_t)(1 << 20));
    float*    bsum  = (float*)(ws + (size_t)(1 << 20) + (128 << 10));
    float*    gx    = (float*)(ws + (size_t)(1 << 20) + (128 << 10) + 4096);

    prep_kernel<<<(GG * DD) / 256, 256, 0, stream>>>(wih, whh, bih, bhh, wih_h, whh_h, bsum);
    gemm_gx<<<(BT / BM) * (GG / BN), 256, 0, stream>>>(x, wih_h, bsum, gx);

    float* hn = out + (size_t)BB * TT * HH;
    float* cn = hn + BB * HH;
    lstm_rec<<<BB, 512, 0, stream>>>(gx, whh_h, out, hn, cn);
}